// Round 5
// baseline (137.037 us; speedup 1.0000x reference)
//
#include <hip/hip_runtime.h>
#include <math.h>

static constexpr int BLK = 256;
static constexpr int R = 8;      // queries per thread
static constexpr int TILE = 256; // scan points staged in LDS per block
static constexpr float BIGW = 1e30f;  // finite sentinel (avoid NaN from inf packing)

__device__ __forceinline__ unsigned f2u(float f) { return __float_as_uint(f); }
__device__ __forceinline__ float u2f(unsigned u) { return __uint_as_float(u); }

// ============================ Path A: 2 dispatches ===========================
// main: pack on the fly, LDS tile, write per-tile partials (no atomics, no init).
// min over d2 == min over m = 0.5|scan|^2 - qry.scan ; d2 = 2*(0.5|qry|^2 + m)
__global__ void __launch_bounds__(BLK) mainA_kernel(
    const float* __restrict__ P, const float* __restrict__ Ps,
    unsigned long long* __restrict__ o2sPart,  // [o2sY][N]
    unsigned* __restrict__ s2oPart,            // [s2oY][M]
    float* __restrict__ out, int N, int M, int o2sX, int o2sBlocks, int s2oX) {
    __shared__ float4 tile[TILE];
    int bx = blockIdx.x;
    if (bx == 0 && threadIdx.x == 0) out[0] = 0.0f;  // read only by finishA (stream order)

    if (bx < o2sBlocks) {
        // ---- original -> sampled: queries = P (N), scan = Ps (M), min+argmin ----
        int ix = bx % o2sX, iy = bx / o2sX;
        int ibase = ix * (BLK * R) + threadIdx.x;
        int j0 = iy * TILE;
        float4 p[R];
        float mmin[R];
#pragma unroll
        for (int r = 0; r < R; ++r) {
            int i = ibase + r * BLK;
            float x = 0.f, y = 0.f, z = 0.f;
            if (i < N) { x = P[3 * i]; y = P[3 * i + 1]; z = P[3 * i + 2]; }
            p[r] = make_float4(-x, -y, -z, 0.5f * (x * x + y * y + z * z));
            mmin[r] = __builtin_inff();
        }
        {
            int idx = j0 + threadIdx.x;
            float x = 0.f, y = 0.f, z = 0.f, w = BIGW;
            if (idx < M) {
                x = Ps[3 * idx]; y = Ps[3 * idx + 1]; z = Ps[3 * idx + 2];
                w = 0.5f * (x * x + y * y + z * z);
            }
            tile[threadIdx.x] = make_float4(x, y, z, w);
        }
        __syncthreads();
#pragma unroll 4
        for (int ii = 0; ii < TILE; ++ii) {
            float4 q = tile[ii];
#pragma unroll
            for (int r = 0; r < R; ++r) {
                float m = fmaf(q.x, p[r].x, fmaf(q.y, p[r].y, fmaf(q.z, p[r].z, q.w)));
                // pack tile-local index into low 8 mantissa bits; one v_min tracks both
                float mp = u2f((f2u(m) & 0xFFFFFF00u) | (unsigned)ii);
                mmin[r] = fminf(mmin[r], mp);
            }
        }
#pragma unroll
        for (int r = 0; r < R; ++r) {
            int i = ibase + r * BLK;
            if (i < N) {
                unsigned u = f2u(mmin[r]);
                unsigned j = (unsigned)j0 + (u & 0xFFu);
                float d2 = fmaxf(2.0f * (p[r].w + mmin[r]), 0.0f);
                o2sPart[(size_t)iy * N + i] = ((unsigned long long)f2u(d2) << 32) | j;
            }
        }
    } else {
        // ---- sampled -> original: queries = Ps (M), scan = P (N), min only ----
        int b = bx - o2sBlocks;
        int ix = b % s2oX, iy = b / s2oX;
        int jbase = ix * (BLK * R) + threadIdx.x;
        int i0 = iy * TILE;
        float4 q[R];
        float mmin[R];
#pragma unroll
        for (int r = 0; r < R; ++r) {
            int j = jbase + r * BLK;
            float x = 0.f, y = 0.f, z = 0.f;
            if (j < M) { x = Ps[3 * j]; y = Ps[3 * j + 1]; z = Ps[3 * j + 2]; }
            q[r] = make_float4(-x, -y, -z, 0.5f * (x * x + y * y + z * z));
            mmin[r] = __builtin_inff();
        }
        {
            int idx = i0 + threadIdx.x;
            float x = 0.f, y = 0.f, z = 0.f, w = BIGW;
            if (idx < N) {
                x = P[3 * idx]; y = P[3 * idx + 1]; z = P[3 * idx + 2];
                w = 0.5f * (x * x + y * y + z * z);
            }
            tile[threadIdx.x] = make_float4(x, y, z, w);
        }
        __syncthreads();
#pragma unroll 4
        for (int ii = 0; ii < TILE; ++ii) {
            float4 p = tile[ii];
#pragma unroll
            for (int r = 0; r < R; ++r) {
                float m = fmaf(p.x, q[r].x, fmaf(p.y, q[r].y, fmaf(p.z, q[r].z, p.w)));
                mmin[r] = fminf(mmin[r], m);
            }
        }
#pragma unroll
        for (int r = 0; r < R; ++r) {
            int j = jbase + r * BLK;
            if (j < M) {
                float d2 = fmaxf(2.0f * (q[r].w + mmin[r]), 0.0f);
                s2oPart[(size_t)iy * M + j] = f2u(d2);
            }
        }
    }
}

// finish: reduce partials per query, weight, block-reduce, one atomicAdd/block.
__global__ void __launch_bounds__(BLK) finishA_kernel(
    const unsigned long long* __restrict__ o2sPart,
    const unsigned* __restrict__ s2oPart, const float* __restrict__ prob,
    float* __restrict__ out, int N, int M, int o2sY, int s2oY) {
    int t = blockIdx.x * BLK + threadIdx.x;
    float acc = 0.0f;
    if (t < M) {
        unsigned best = 0xFFFFFFFFu;
        for (int iy = 0; iy < s2oY; ++iy)
            best = min(best, s2oPart[(size_t)iy * M + t]);
        acc = sqrtf(u2f(best)) * prob[t];
    } else if (t < M + N) {
        int i = t - M;
        unsigned long long best = ~0ull;
        for (int iy = 0; iy < o2sY; ++iy)
            best = min(best, o2sPart[(size_t)iy * N + i]);
        float d2 = u2f((unsigned)(best >> 32));
        unsigned jj = (unsigned)(best & 0xFFFFFFFFu);
        acc = sqrtf(d2) * prob[jj];
    }
#pragma unroll
    for (int off = 32; off > 0; off >>= 1) acc += __shfl_down(acc, off, 64);
    __shared__ float wsum[BLK / 64];
    int lane = threadIdx.x & 63, wave = threadIdx.x >> 6;
    if (lane == 0) wsum[wave] = acc;
    __syncthreads();
    if (threadIdx.x == 0) {
        float s = 0.0f;
#pragma unroll
        for (int w = 0; w < BLK / 64; ++w) s += wsum[w];
        atomicAdd(out, s);
    }
}

// ===================== Path B: proven round-3 fallback =======================
__global__ void prepB_kernel(const float* __restrict__ P, const float* __restrict__ Ps,
                             float4* __restrict__ pp, float4* __restrict__ psp,
                             unsigned long long* __restrict__ o2s, unsigned* __restrict__ s2o,
                             float* __restrict__ out, int N, int M) {
    int i = blockIdx.x * blockDim.x + threadIdx.x;
    if (i < N) {
        float x = P[3 * i], y = P[3 * i + 1], z = P[3 * i + 2];
        pp[i] = make_float4(x, y, z, 0.5f * (x * x + y * y + z * z));
        o2s[i] = ~0ull;
    }
    if (i < M) {
        float x = Ps[3 * i], y = Ps[3 * i + 1], z = Ps[3 * i + 2];
        psp[i] = make_float4(x, y, z, 0.5f * (x * x + y * y + z * z));
        s2o[i] = 0xFFFFFFFFu;
    }
    if (i == 0) out[0] = 0.0f;
}

__global__ void __launch_bounds__(BLK) mainB_kernel(
    const float4* __restrict__ pp, const float4* __restrict__ psp,
    unsigned long long* __restrict__ o2s, unsigned* __restrict__ s2o,
    int N, int M, int o2sX, int o2sBlocks, int s2oX) {
    __shared__ float4 tile[TILE];
    int bx = blockIdx.x;
    if (bx < o2sBlocks) {
        int ix = bx % o2sX, iy = bx / o2sX;
        int ibase = ix * (BLK * R) + threadIdx.x;
        int j0 = iy * TILE;
        float4 p[R];
        float mmin[R];
        int mj[R];
#pragma unroll
        for (int r = 0; r < R; ++r) {
            int i = ibase + r * BLK;
            float4 t = (i < N) ? pp[i] : make_float4(0.f, 0.f, 0.f, 0.f);
            p[r] = make_float4(-t.x, -t.y, -t.z, t.w);
            mmin[r] = __builtin_inff();
            mj[r] = j0;
        }
        int idx = j0 + threadIdx.x;
        tile[threadIdx.x] =
            (idx < M) ? psp[idx] : make_float4(0.f, 0.f, 0.f, BIGW);
        __syncthreads();
#pragma unroll 4
        for (int ii = 0; ii < TILE; ++ii) {
            float4 q = tile[ii];
#pragma unroll
            for (int r = 0; r < R; ++r) {
                float m = fmaf(q.x, p[r].x, fmaf(q.y, p[r].y, fmaf(q.z, p[r].z, q.w)));
                if (m < mmin[r]) { mmin[r] = m; mj[r] = j0 + ii; }
            }
        }
#pragma unroll
        for (int r = 0; r < R; ++r) {
            int i = ibase + r * BLK;
            if (i < N) {
                float d2 = fmaxf(2.0f * (p[r].w + mmin[r]), 0.0f);
                unsigned long long key =
                    ((unsigned long long)f2u(d2) << 32) | (unsigned)mj[r];
                atomicMin(&o2s[i], key);
            }
        }
    } else {
        int b = bx - o2sBlocks;
        int ix = b % s2oX, iy = b / s2oX;
        int jbase = ix * (BLK * R) + threadIdx.x;
        int i0 = iy * TILE;
        float4 q[R];
        float mmin[R];
#pragma unroll
        for (int r = 0; r < R; ++r) {
            int j = jbase + r * BLK;
            float4 t = (j < M) ? psp[j] : make_float4(0.f, 0.f, 0.f, 0.f);
            q[r] = make_float4(-t.x, -t.y, -t.z, t.w);
            mmin[r] = __builtin_inff();
        }
        int idx = i0 + threadIdx.x;
        tile[threadIdx.x] =
            (idx < N) ? pp[idx] : make_float4(0.f, 0.f, 0.f, BIGW);
        __syncthreads();
#pragma unroll 4
        for (int ii = 0; ii < TILE; ++ii) {
            float4 p = tile[ii];
#pragma unroll
            for (int r = 0; r < R; ++r) {
                float m = fmaf(p.x, q[r].x, fmaf(p.y, q[r].y, fmaf(p.z, q[r].z, p.w)));
                mmin[r] = fminf(mmin[r], m);
            }
        }
#pragma unroll
        for (int r = 0; r < R; ++r) {
            int j = jbase + r * BLK;
            if (j < M) {
                float d2 = fmaxf(2.0f * (q[r].w + mmin[r]), 0.0f);
                atomicMin(&s2o[j], f2u(d2));
            }
        }
    }
}

__global__ void finishB_kernel(const unsigned* __restrict__ s2o,
                               const unsigned long long* __restrict__ o2s,
                               const float* __restrict__ prob,
                               float* __restrict__ out, int N, int M) {
    int t = blockIdx.x * BLK + threadIdx.x;
    float acc = 0.0f;
    if (t < M) {
        acc = sqrtf(u2f(s2o[t])) * prob[t];
    } else if (t < M + N) {
        unsigned long long key = o2s[t - M];
        float d2 = u2f((unsigned)(key >> 32));
        unsigned jj = (unsigned)(key & 0xFFFFFFFFu);
        acc = sqrtf(d2) * prob[jj];
    }
#pragma unroll
    for (int off = 32; off > 0; off >>= 1) acc += __shfl_down(acc, off, 64);
    __shared__ float wsum[BLK / 64];
    int lane = threadIdx.x & 63, wave = threadIdx.x >> 6;
    if (lane == 0) wsum[wave] = acc;
    __syncthreads();
    if (threadIdx.x == 0) {
        float s = 0.0f;
#pragma unroll
        for (int w = 0; w < BLK / 64; ++w) s += wsum[w];
        atomicAdd(out, s);
    }
}

extern "C" void kernel_launch(void* const* d_in, const int* in_sizes, int n_in,
                              void* d_out, int out_size, void* d_ws, size_t ws_size,
                              hipStream_t stream) {
    const float* P = (const float*)d_in[0];
    const float* Ps = (const float*)d_in[1];
    const float* prob = (const float*)d_in[2];
    int N = in_sizes[0] / 3;  // 32768
    int M = in_sizes[1] / 3;  // 8192
    float* out = (float*)d_out;

    int o2sX = (N + BLK * R - 1) / (BLK * R);   // 16
    int o2sY = (M + TILE - 1) / TILE;           // 32
    int s2oX = (M + BLK * R - 1) / (BLK * R);   // 4
    int s2oY = (N + TILE - 1) / TILE;           // 128
    int o2sBlocks = o2sX * o2sY;                // 512
    int total = o2sBlocks + s2oX * s2oY;        // 1024

    size_t needA = (size_t)o2sY * N * 8 + (size_t)s2oY * M * 4;  // 12 MB
    if (ws_size >= needA) {
        // Path A: 2 dispatches, partials in ws, no init kernel, no atomicMin.
        unsigned long long* o2sPart = (unsigned long long*)d_ws;
        unsigned* s2oPart = (unsigned*)((char*)d_ws + (size_t)o2sY * N * 8);
        mainA_kernel<<<total, BLK, 0, stream>>>(P, Ps, o2sPart, s2oPart, out, N, M,
                                                o2sX, o2sBlocks, s2oX);
        finishA_kernel<<<(N + M + BLK - 1) / BLK, BLK, 0, stream>>>(
            o2sPart, s2oPart, prob, out, N, M, o2sY, s2oY);
    } else {
        // Path B: round-3 proven structure.
        char* ws = (char*)d_ws;
        float4* pp = (float4*)ws;
        float4* psp = (float4*)(ws + (size_t)N * 16);
        unsigned long long* o2s =
            (unsigned long long*)(ws + (size_t)N * 16 + (size_t)M * 16);
        unsigned* s2o =
            (unsigned*)(ws + (size_t)N * 16 + (size_t)M * 16 + (size_t)N * 8);
        int prepBlocks = (max(N, M) + BLK - 1) / BLK;
        prepB_kernel<<<prepBlocks, BLK, 0, stream>>>(P, Ps, pp, psp, o2s, s2o, out, N, M);
        mainB_kernel<<<total, BLK, 0, stream>>>(pp, psp, o2s, s2o, N, M,
                                                o2sX, o2sBlocks, s2oX);
        finishB_kernel<<<(N + M + BLK - 1) / BLK, BLK, 0, stream>>>(s2o, o2s, prob,
                                                                    out, N, M);
    }
}

// Round 6
// 112.331 us; speedup vs baseline: 1.2199x; 1.2199x over previous
//
#include <hip/hip_runtime.h>
#include <math.h>

static constexpr int BLK = 256;
static constexpr int R = 8;      // queries per thread (4 packed pairs)
static constexpr int RP = R / 2; // query pairs
static constexpr int TILE = 256; // scan points staged in LDS per block
static constexpr float BIGW = 1e30f;  // finite sentinel

typedef float f32x2 __attribute__((ext_vector_type(2)));
typedef float f32x4 __attribute__((ext_vector_type(4)));

__device__ __forceinline__ unsigned f2u(float f) { return __float_as_uint(f); }
__device__ __forceinline__ float u2f(unsigned u) { return __uint_as_float(u); }

// VOP3P packed fp32 FMA with op_sel half-broadcasts of the scan point.
// Semantics: D.lo = S0[op_sel[0]]*S1[op_sel[1]] + S2[op_sel[2]]
//            D.hi = S0[op_sel_hi[0]]*S1[op_sel_hi[1]] + S2[op_sel_hi[2]]
// d = {z,z} * pz2 + {w,w}   (zw = {z,w} aligned half of the b128 tile read)
__device__ __forceinline__ f32x2 pk_fma_zw(f32x2 zw, f32x2 pz2) {
    f32x2 d;
    asm("v_pk_fma_f32 %0, %1, %2, %1 op_sel:[0,0,1] op_sel_hi:[0,1,1]"
        : "=v"(d) : "v"(zw), "v"(pz2));
    return d;
}
// d = {y,y} * py2 + c   (xy = {x,y}; broadcast hi half = y)
__device__ __forceinline__ f32x2 pk_fma_y(f32x2 xy, f32x2 py2, f32x2 c) {
    f32x2 d;
    asm("v_pk_fma_f32 %0, %1, %2, %3 op_sel:[1,0,0] op_sel_hi:[1,1,1]"
        : "=v"(d) : "v"(xy), "v"(py2), "v"(c));
    return d;
}
// d = {x,x} * px2 + c   (broadcast lo half = x)
__device__ __forceinline__ f32x2 pk_fma_x(f32x2 xy, f32x2 px2, f32x2 c) {
    f32x2 d;
    asm("v_pk_fma_f32 %0, %1, %2, %3 op_sel:[0,0,0] op_sel_hi:[0,1,1]"
        : "=v"(d) : "v"(xy), "v"(px2), "v"(c));
    return d;
}

// prep: sentinels + out=0 only (288 KB ws total; no point staging).
__global__ void prep_kernel(unsigned long long* __restrict__ o2s,
                            unsigned* __restrict__ s2o,
                            float* __restrict__ out, int N, int M) {
    int i = blockIdx.x * blockDim.x + threadIdx.x;
    if (i < N) o2s[i] = ~0ull;
    if (i < M) s2o[i] = 0xFFFFFFFFu;
    if (i == 0) out[0] = 0.0f;
}

// Fused bidirectional NN scan. min over d2 == min over m = 0.5|scan|^2 - qry.scan
// d2 = 2*(0.5|qry|^2 + m). Queries packed in pairs (VOP3P), scan point broadcast
// via op_sel from the {x,y}/{z,w} halves of the ds_read_b128 tile entry.
__global__ void __launch_bounds__(BLK) main_kernel(
    const float* __restrict__ P, const float* __restrict__ Ps,
    unsigned long long* __restrict__ o2s, unsigned* __restrict__ s2o,
    int N, int M, int o2sX, int o2sBlocks, int s2oX) {
    __shared__ f32x4 tile[TILE];
    int bx = blockIdx.x;

    if (bx < o2sBlocks) {
        // ---- original -> sampled: queries = P (N), scan = Ps (M), min+argmin ----
        int ix = bx % o2sX, iy = bx / o2sX;
        int ibase = ix * (BLK * R) + threadIdx.x;
        int j0 = iy * TILE;
        f32x2 px2[RP], py2[RP], pz2[RP], pw2[RP];
        f32x2 mmin[RP];
#pragma unroll
        for (int rp = 0; rp < RP; ++rp) {
            float xa = 0.f, ya = 0.f, za = 0.f, xb = 0.f, yb = 0.f, zb = 0.f;
            int ia = ibase + (2 * rp) * BLK, ib = ibase + (2 * rp + 1) * BLK;
            if (ia < N) { xa = P[3 * ia]; ya = P[3 * ia + 1]; za = P[3 * ia + 2]; }
            if (ib < N) { xb = P[3 * ib]; yb = P[3 * ib + 1]; zb = P[3 * ib + 2]; }
            px2[rp] = (f32x2){-xa, -xb};
            py2[rp] = (f32x2){-ya, -yb};
            pz2[rp] = (f32x2){-za, -zb};
            pw2[rp] = (f32x2){0.5f * (xa * xa + ya * ya + za * za),
                              0.5f * (xb * xb + yb * yb + zb * zb)};
            mmin[rp] = (f32x2){__builtin_inff(), __builtin_inff()};
        }
        {
            int idx = j0 + threadIdx.x;
            float x = 0.f, y = 0.f, z = 0.f, w = BIGW;
            if (idx < M) {
                x = Ps[3 * idx]; y = Ps[3 * idx + 1]; z = Ps[3 * idx + 2];
                w = 0.5f * (x * x + y * y + z * z);
            }
            tile[threadIdx.x] = (f32x4){x, y, z, w};
        }
        __syncthreads();
#pragma unroll 8
        for (int ii = 0; ii < TILE; ++ii) {
            f32x4 q = tile[ii];
            f32x2 xy = __builtin_shufflevector(q, q, 0, 1);
            f32x2 zw = __builtin_shufflevector(q, q, 2, 3);
#pragma unroll
            for (int rp = 0; rp < RP; ++rp) {
                f32x2 m2 = pk_fma_x(xy, px2[rp],
                            pk_fma_y(xy, py2[rp], pk_fma_zw(zw, pz2[rp])));
                // pack tile-local index into low 8 mantissa bits; min tracks both
                float mlo = u2f((f2u(m2.x) & 0xFFFFFF00u) | (unsigned)ii);
                float mhi = u2f((f2u(m2.y) & 0xFFFFFF00u) | (unsigned)ii);
                mmin[rp].x = fminf(mmin[rp].x, mlo);
                mmin[rp].y = fminf(mmin[rp].y, mhi);
            }
        }
#pragma unroll
        for (int rp = 0; rp < RP; ++rp) {
            int ia = ibase + (2 * rp) * BLK, ib = ibase + (2 * rp + 1) * BLK;
            if (ia < N) {
                unsigned j = (unsigned)j0 + (f2u(mmin[rp].x) & 0xFFu);
                float d2 = fmaxf(2.0f * (pw2[rp].x + mmin[rp].x), 0.0f);
                atomicMin(&o2s[ia], ((unsigned long long)f2u(d2) << 32) | j);
            }
            if (ib < N) {
                unsigned j = (unsigned)j0 + (f2u(mmin[rp].y) & 0xFFu);
                float d2 = fmaxf(2.0f * (pw2[rp].y + mmin[rp].y), 0.0f);
                atomicMin(&o2s[ib], ((unsigned long long)f2u(d2) << 32) | j);
            }
        }
    } else {
        // ---- sampled -> original: queries = Ps (M), scan = P (N), min only ----
        int b = bx - o2sBlocks;
        int ix = b % s2oX, iy = b / s2oX;
        int jbase = ix * (BLK * R) + threadIdx.x;
        int i0 = iy * TILE;
        f32x2 qx2[RP], qy2[RP], qz2[RP], qw2[RP];
        f32x2 mmin[RP];
#pragma unroll
        for (int rp = 0; rp < RP; ++rp) {
            float xa = 0.f, ya = 0.f, za = 0.f, xb = 0.f, yb = 0.f, zb = 0.f;
            int ja = jbase + (2 * rp) * BLK, jb = jbase + (2 * rp + 1) * BLK;
            if (ja < M) { xa = Ps[3 * ja]; ya = Ps[3 * ja + 1]; za = Ps[3 * ja + 2]; }
            if (jb < M) { xb = Ps[3 * jb]; yb = Ps[3 * jb + 1]; zb = Ps[3 * jb + 2]; }
            qx2[rp] = (f32x2){-xa, -xb};
            qy2[rp] = (f32x2){-ya, -yb};
            qz2[rp] = (f32x2){-za, -zb};
            qw2[rp] = (f32x2){0.5f * (xa * xa + ya * ya + za * za),
                              0.5f * (xb * xb + yb * yb + zb * zb)};
            mmin[rp] = (f32x2){__builtin_inff(), __builtin_inff()};
        }
        {
            int idx = i0 + threadIdx.x;
            float x = 0.f, y = 0.f, z = 0.f, w = BIGW;
            if (idx < N) {
                x = P[3 * idx]; y = P[3 * idx + 1]; z = P[3 * idx + 2];
                w = 0.5f * (x * x + y * y + z * z);
            }
            tile[threadIdx.x] = (f32x4){x, y, z, w};
        }
        __syncthreads();
#pragma unroll 8
        for (int ii = 0; ii < TILE; ++ii) {
            f32x4 p = tile[ii];
            f32x2 xy = __builtin_shufflevector(p, p, 0, 1);
            f32x2 zw = __builtin_shufflevector(p, p, 2, 3);
#pragma unroll
            for (int rp = 0; rp < RP; ++rp) {
                f32x2 m2 = pk_fma_x(xy, qx2[rp],
                            pk_fma_y(xy, qy2[rp], pk_fma_zw(zw, qz2[rp])));
                mmin[rp].x = fminf(mmin[rp].x, m2.x);
                mmin[rp].y = fminf(mmin[rp].y, m2.y);
            }
        }
#pragma unroll
        for (int rp = 0; rp < RP; ++rp) {
            int ja = jbase + (2 * rp) * BLK, jb = jbase + (2 * rp + 1) * BLK;
            if (ja < M) {
                float d2 = fmaxf(2.0f * (qw2[rp].x + mmin[rp].x), 0.0f);
                atomicMin(&s2o[ja], f2u(d2));
            }
            if (jb < M) {
                float d2 = fmaxf(2.0f * (qw2[rp].y + mmin[rp].y), 0.0f);
                atomicMin(&s2o[jb], f2u(d2));
            }
        }
    }
}

// finish: one load per query, weight, block-reduce, one atomicAdd per block.
__global__ void finish_kernel(const unsigned* __restrict__ s2o,
                              const unsigned long long* __restrict__ o2s,
                              const float* __restrict__ prob,
                              float* __restrict__ out, int N, int M) {
    int t = blockIdx.x * BLK + threadIdx.x;
    float acc = 0.0f;
    if (t < M) {
        acc = sqrtf(u2f(s2o[t])) * prob[t];
    } else if (t < M + N) {
        unsigned long long key = o2s[t - M];
        float d2 = u2f((unsigned)(key >> 32));
        unsigned jj = (unsigned)(key & 0xFFFFFFFFu);
        acc = sqrtf(d2) * prob[jj];
    }
#pragma unroll
    for (int off = 32; off > 0; off >>= 1) acc += __shfl_down(acc, off, 64);
    __shared__ float wsum[BLK / 64];
    int lane = threadIdx.x & 63, wave = threadIdx.x >> 6;
    if (lane == 0) wsum[wave] = acc;
    __syncthreads();
    if (threadIdx.x == 0) {
        float s = 0.0f;
#pragma unroll
        for (int w = 0; w < BLK / 64; ++w) s += wsum[w];
        atomicAdd(out, s);
    }
}

extern "C" void kernel_launch(void* const* d_in, const int* in_sizes, int n_in,
                              void* d_out, int out_size, void* d_ws, size_t ws_size,
                              hipStream_t stream) {
    const float* P = (const float*)d_in[0];
    const float* Ps = (const float*)d_in[1];
    const float* prob = (const float*)d_in[2];
    int N = in_sizes[0] / 3;  // 32768
    int M = in_sizes[1] / 3;  // 8192
    float* out = (float*)d_out;

    unsigned long long* o2s = (unsigned long long*)d_ws;          // N * 8 B
    unsigned* s2o = (unsigned*)((char*)d_ws + (size_t)N * 8);     // M * 4 B

    int o2sX = (N + BLK * R - 1) / (BLK * R);   // 16
    int o2sY = (M + TILE - 1) / TILE;           // 32
    int s2oX = (M + BLK * R - 1) / (BLK * R);   // 4
    int s2oY = (N + TILE - 1) / TILE;           // 128
    int o2sBlocks = o2sX * o2sY;                // 512
    int total = o2sBlocks + s2oX * s2oY;        // 1024

    prep_kernel<<<(N + BLK - 1) / BLK, BLK, 0, stream>>>(o2s, s2o, out, N, M);
    main_kernel<<<total, BLK, 0, stream>>>(P, Ps, o2s, s2o, N, M,
                                           o2sX, o2sBlocks, s2oX);
    finish_kernel<<<(N + M + BLK - 1) / BLK, BLK, 0, stream>>>(s2o, o2s, prob,
                                                               out, N, M);
}